// Round 4
// baseline (576.153 us; speedup 1.0000x reference)
//
#include <hip/hip_runtime.h>
#include <hip/hip_bf16.h>

constexpr int NN = 50000;
constexpr int NE = 1600000;
constexpr int DI = 512;
constexpr int DH = 256;
constexpr int DO = 64;

constexpr int G1_BLOCKS = ((NN + 127) / 128) * (DH / 128);  // 782
constexpr int SC_BLOCKS = 2048;                             // multiple of 8

typedef __attribute__((ext_vector_type(8))) short short8;
typedef __attribute__((ext_vector_type(4))) float f32x4;

__device__ inline ushort f2b(float f) {          // fp32 -> bf16 bits, RNE
    uint u = __float_as_uint(f);
    u += 0x7fffu + ((u >> 16) & 1u);
    return (ushort)(u >> 16);
}
__device__ inline float b2f(ushort u) {
    return __uint_as_float((uint)u << 16);
}

// ---------------- CSR build ----------------

__global__ void k_hist(const int* __restrict__ rows, int* __restrict__ counts) {
    int i = blockIdx.x * blockDim.x + threadIdx.x;
    int stride = gridDim.x * blockDim.x;
    const int4* r4 = (const int4*)rows;
    for (; i < NE / 4; i += stride) {
        int4 v = r4[i];
        atomicAdd(&counts[v.x], 1);
        atomicAdd(&counts[v.y], 1);
        atomicAdd(&counts[v.z], 1);
        atomicAdd(&counts[v.w], 1);
    }
}

__global__ __launch_bounds__(1024) void k_scan(const int* __restrict__ counts,
                                               int* __restrict__ row_ptr,
                                               int* __restrict__ cursor, int n) {
    const int C = (n + 1023) / 1024;
    int t = threadIdx.x;
    int lo = t * C;
    int hi = min(lo + C, n);
    int s = 0;
    for (int i = lo; i < hi; ++i) s += counts[i];
    __shared__ int buf[1024];
    buf[t] = s;
    __syncthreads();
    for (int off = 1; off < 1024; off <<= 1) {
        int v = (t >= off) ? buf[t - off] : 0;
        __syncthreads();
        buf[t] += v;
        __syncthreads();
    }
    int excl = buf[t] - s;
    for (int i = lo; i < hi; ++i) {
        row_ptr[i] = excl;
        cursor[i]  = excl;
        excl += counts[i];
    }
    if (t == 1023) row_ptr[n] = buf[1023];
}

// ---------------- fat kernel: GEMM1 (MFMA) blocks + XCD-local scatter blocks ----------------

__global__ __launch_bounds__(256) void k_gemm1_scatter(
        const float* __restrict__ X, const float* __restrict__ W,
        const float* __restrict__ B, ushort* __restrict__ H,
        const int* __restrict__ er, const int* __restrict__ ec,
        const float* __restrict__ ev, int* __restrict__ cur,
        int2* __restrict__ ev8) {
    const int bid = blockIdx.x;
    if (bid < G1_BLOCKS) {
        __shared__ ushort Xs[128 * 32];
        __shared__ ushort Ws[128 * 32];
        const int bm = (bid >> 1) * 128;
        const int bn = (bid & 1) * 128;
        const int tid = threadIdx.x;
        const int wid = tid >> 6, lane = tid & 63;
        const int wm = wid >> 1, wn = wid & 1;
        const int lr = lane & 15, lg = lane >> 4;

        f32x4 acc[4][4];
        #pragma unroll
        for (int i = 0; i < 4; ++i)
            #pragma unroll
            for (int j = 0; j < 4; ++j)
                acc[i][j] = (f32x4){0.f, 0.f, 0.f, 0.f};

        for (int kt = 0; kt < DI; kt += 32) {
            #pragma unroll
            for (int c = 0; c < 4; ++c) {
                int id = tid + c * 256;
                int row = id >> 3, kc = id & 7;
                int gr = bm + row;
                float4 v = {0.f, 0.f, 0.f, 0.f};
                if (gr < NN) v = *(const float4*)(X + (size_t)gr * DI + kt + kc * 4);
                ushort4 p = make_ushort4(f2b(v.x), f2b(v.y), f2b(v.z), f2b(v.w));
                *(ushort4*)&Xs[row * 32 + kc * 4] = p;
            }
            #pragma unroll
            for (int c = 0; c < 2; ++c) {
                int id = tid + c * 256;
                int n = id & 127, g = id >> 7;
                short8 p;
                #pragma unroll
                for (int e = 0; e < 8; ++e)
                    p[e] = (short)f2b(W[(size_t)(kt + g * 8 + e) * DH + bn + n]);
                *(short8*)&Ws[n * 32 + g * 8] = p;
            }
            __syncthreads();

            short8 a[4], b[4];
            #pragma unroll
            for (int f = 0; f < 4; ++f) {
                a[f] = *(short8*)&Xs[(wm * 64 + f * 16 + lr) * 32 + lg * 8];
                b[f] = *(short8*)&Ws[(wn * 64 + f * 16 + lr) * 32 + lg * 8];
            }
            #pragma unroll
            for (int i = 0; i < 4; ++i)
                #pragma unroll
                for (int j = 0; j < 4; ++j)
                    acc[i][j] = __builtin_amdgcn_mfma_f32_16x16x32_bf16(a[i], b[j], acc[i][j], 0, 0, 0);
            __syncthreads();
        }

        #pragma unroll
        for (int i = 0; i < 4; ++i) {
            int r0 = bm + wm * 64 + i * 16 + lg * 4;
            #pragma unroll
            for (int j = 0; j < 4; ++j) {
                int col = bn + wn * 64 + j * 16 + lr;
                float bias = B[col];
                #pragma unroll
                for (int e = 0; e < 4; ++e) {
                    int r = r0 + e;
                    if (r < NN) H[(size_t)r * DH + col] = f2b(acc[i][j][e] + bias);
                }
            }
        }
    } else {
        // scatter: rows partitioned by XCD (blockIdx % 8) -> each XCD's write
        // window (~1.6 MB of ev8) stays L2-resident, full-line writebacks.
        const int sb = bid - G1_BLOCKS;
        const int g  = bid & 7;
        const int lb = sb >> 3;
        const int lo = g * (NN / 8), hi = lo + (NN / 8);
        const int tid = threadIdx.x;
        const int4* er4 = (const int4*)er;
        const int NQ = NE / 4;
        for (int q = lb * 256 + tid; q < NQ; q += (SC_BLOCKS / 8) * 256) {
            int4 r4 = er4[q];
            int base = q * 4;
            #pragma unroll
            for (int e = 0; e < 4; ++e) {
                int r = (e == 0) ? r4.x : (e == 1) ? r4.y : (e == 2) ? r4.z : r4.w;
                if (r >= lo && r < hi) {
                    int p = atomicAdd(&cur[r], 1);
                    ev8[p] = make_int2(ec[base + e], __float_as_int(ev[base + e]));
                }
            }
        }
    }
}

// ---------------- SpMM1 + ReLU, XCD-segment-split over the 256 dims ----------------
// block b handles dim segment (b%8): per row, gather only that row-segment
// (one 64 B line per edge) -> per-XCD gather footprint 3.2 MB, L2-resident.
// wave = 8 edge slots x 8 dim-lanes (ushort4 each).

__global__ __launch_bounds__(256) void k_spmm1(const int* __restrict__ rp,
                                               const int2* __restrict__ ev8,
                                               const ushort* __restrict__ H,
                                               ushort* __restrict__ O) {
    const int seg = blockIdx.x & 7;
    const int r = (blockIdx.x >> 3) * 4 + (threadIdx.x >> 6);
    const int lane = threadIdx.x & 63;
    const int slot = lane >> 3;      // 0..7 edge slot
    const int dq = lane & 7;         // dim quad within segment (4 dims)
    int s = rp[r], e = rp[r + 1];
    float a0 = 0.f, a1 = 0.f, a2 = 0.f, a3 = 0.f;
    const ushort* base = H + seg * 32 + dq * 4;
    for (int i = s + slot; i < e; i += 8) {
        int2 ed = ev8[i];
        ushort4 h = *(const ushort4*)(base + (size_t)ed.x * DH);
        float v = __int_as_float(ed.y);
        a0 += v * b2f(h.x); a1 += v * b2f(h.y); a2 += v * b2f(h.z); a3 += v * b2f(h.w);
    }
    #pragma unroll
    for (int m = 8; m < 64; m <<= 1) {
        a0 += __shfl_xor(a0, m); a1 += __shfl_xor(a1, m);
        a2 += __shfl_xor(a2, m); a3 += __shfl_xor(a3, m);
    }
    if (slot == 0) {
        ushort4 o = make_ushort4(f2b(fmaxf(a0, 0.f)), f2b(fmaxf(a1, 0.f)),
                                 f2b(fmaxf(a2, 0.f)), f2b(fmaxf(a3, 0.f)));
        *(ushort4*)(O + (size_t)r * DH + seg * 32 + dq * 4) = o;
    }
}

// ---------------- GEMM2 (MFMA): h2 = h1b @ W2 + b2 ----------------
// BM=128, BN=64(=DO), BK=32; W2 staged bf16 in LDS once; A read direct.

__global__ __launch_bounds__(256) void k_gemm2(const ushort* __restrict__ HB,
                                               const float* __restrict__ W2,
                                               const float* __restrict__ B2,
                                               ushort* __restrict__ H2) {
    __shared__ ushort Ws[64 * 264];   // [n][k], stride 264 breaks bank conflicts
    const int tid = threadIdx.x;
    for (int idx = tid; idx < DH * DO; idx += 256) {
        int k = idx >> 6, n = idx & 63;
        Ws[n * 264 + k] = f2b(W2[idx]);
    }
    __syncthreads();
    const int wid = tid >> 6, lane = tid & 63;
    const int lr = lane & 15, lg = lane >> 4;
    const int r0 = blockIdx.x * 128 + wid * 32;

    f32x4 acc[2][4];
    #pragma unroll
    for (int i = 0; i < 2; ++i)
        #pragma unroll
        for (int j = 0; j < 4; ++j)
            acc[i][j] = (f32x4){0.f, 0.f, 0.f, 0.f};

    for (int kt = 0; kt < DH; kt += 32) {
        short8 a[2], b[4];
        #pragma unroll
        for (int f = 0; f < 2; ++f) {
            int row = r0 + f * 16 + lr;
            a[f] = (row < NN) ? *(const short8*)(HB + (size_t)row * DH + kt + lg * 8)
                              : (short8){0,0,0,0,0,0,0,0};
        }
        #pragma unroll
        for (int j = 0; j < 4; ++j)
            b[j] = *(const short8*)&Ws[(j * 16 + lr) * 264 + kt + lg * 8];
        #pragma unroll
        for (int i = 0; i < 2; ++i)
            #pragma unroll
            for (int j = 0; j < 4; ++j)
                acc[i][j] = __builtin_amdgcn_mfma_f32_16x16x32_bf16(a[i], b[j], acc[i][j], 0, 0, 0);
    }

    #pragma unroll
    for (int i = 0; i < 2; ++i) {
        #pragma unroll
        for (int j = 0; j < 4; ++j) {
            int col = j * 16 + lr;
            float bias = B2[col];
            #pragma unroll
            for (int e = 0; e < 4; ++e) {
                int row = r0 + i * 16 + lg * 4 + e;
                if (row < NN) H2[(size_t)row * DO + col] = f2b(acc[i][j][e] + bias);
            }
        }
    }
}

// ---------------- SpMM2: out = A @ h2 (fp32 out); h2 table 3.2 MB, L2-fits ----------------

__global__ __launch_bounds__(256) void k_spmm_out(const int* __restrict__ rp,
                                                  const int2* __restrict__ ev8,
                                                  const ushort* __restrict__ H2,
                                                  float* __restrict__ OUT) {
    int r = blockIdx.x * 4 + (threadIdx.x >> 6);
    int lane = threadIdx.x & 63;
    int g = lane >> 4;          // edge slot 0..3
    int q = lane & 15;          // dim quad
    int s = rp[r], e = rp[r + 1];
    float a0 = 0.f, a1 = 0.f, a2 = 0.f, a3 = 0.f;

    for (int i = s + g; i < e; i += 4) {
        int2 ed = ev8[i];
        ushort4 h = *((const ushort4*)(H2 + (size_t)ed.x * DO) + q);
        float v = __int_as_float(ed.y);
        a0 += v * b2f(h.x); a1 += v * b2f(h.y); a2 += v * b2f(h.z); a3 += v * b2f(h.w);
    }
    a0 += __shfl_xor(a0, 16); a0 += __shfl_xor(a0, 32);
    a1 += __shfl_xor(a1, 16); a1 += __shfl_xor(a1, 32);
    a2 += __shfl_xor(a2, 16); a2 += __shfl_xor(a2, 32);
    a3 += __shfl_xor(a3, 16); a3 += __shfl_xor(a3, 32);
    if (g == 0) {
        *((float4*)(OUT + (size_t)r * DO) + q) = make_float4(a0, a1, a2, a3);
    }
}

// ---------------- launch ----------------

extern "C" void kernel_launch(void* const* d_in, const int* in_sizes, int n_in,
                              void* d_out, int out_size, void* d_ws, size_t ws_size,
                              hipStream_t stream) {
    const float* x  = (const float*)d_in[0];
    const int*   er = (const int*)d_in[1];
    const int*   ec = (const int*)d_in[2];
    const float* ev = (const float*)d_in[3];
    const float* W1 = (const float*)d_in[4];
    const float* b1 = (const float*)d_in[5];
    const float* W2 = (const float*)d_in[6];
    const float* b2 = (const float*)d_in[7];
    float* out = (float*)d_out;

    char* ws = (char*)d_ws;
    ushort* h1  = (ushort*)ws; ws += (size_t)NN * DH * 2;                   // 25.6 MB
    ushort* h1b = (ushort*)ws; ws += (size_t)NN * DH * 2;                   // 25.6 MB
    ushort* h2  = (ushort*)ws; ws += (size_t)NN * DO * 2;                   //  6.4 MB
    int2*  ev8 = (int2*)ws;   ws += (size_t)NE * 8;                         // 12.8 MB
    int* counts = (int*)ws;   ws += ((size_t)NN * 4 + 255) & ~(size_t)255;
    int* rp     = (int*)ws;   ws += ((size_t)(NN + 1) * 4 + 255) & ~(size_t)255;
    int* cur    = (int*)ws;   ws += ((size_t)NN * 4 + 255) & ~(size_t)255;

    hipMemsetAsync(counts, 0, (size_t)NN * 4, stream);
    k_hist<<<1024, 256, 0, stream>>>(er, counts);
    k_scan<<<1, 1024, 0, stream>>>(counts, rp, cur, NN);
    k_gemm1_scatter<<<G1_BLOCKS + SC_BLOCKS, 256, 0, stream>>>(
        x, W1, b1, h1, er, ec, ev, cur, ev8);
    k_spmm1<<<(NN / 4) * 8, 256, 0, stream>>>(rp, ev8, h1, h1b);
    k_gemm2<<<(NN + 127) / 128, 256, 0, stream>>>(h1b, W2, b2, h2);
    k_spmm_out<<<NN / 4, 256, 0, stream>>>(rp, ev8, h2, out);
}

// Round 5
// 450.229 us; speedup vs baseline: 1.2797x; 1.2797x over previous
//
#include <hip/hip_runtime.h>
#include <hip/hip_bf16.h>

constexpr int NN = 50000;
constexpr int NE = 1600000;
constexpr int DI = 512;
constexpr int DH = 256;
constexpr int DO = 64;

constexpr int NCH = 16;                  // column chunks: chunk = col >> 12 (13 used)
constexpr int NC  = NN * NCH;            // 800000 keys
constexpr int SCAN_B = (NC + 4095) / 4096;   // 196 blocks
constexpr int G1_BLOCKS = ((NN + 127) / 128) * (DH / 128);  // 782
constexpr int SC_BLOCKS = 2048;
constexpr int P_BLOCKS  = 2048;          // persistent spmm1 blocks (8/CU)
constexpr int P_WAVES   = P_BLOCKS * 4;  // 8192
constexpr int ROWS_PW   = (NN + P_WAVES - 1) / P_WAVES;  // 7

typedef __attribute__((ext_vector_type(8))) short short8;
typedef __attribute__((ext_vector_type(4))) float f32x4;

__device__ inline ushort f2b(float f) {          // fp32 -> bf16 bits, RNE
    uint u = __float_as_uint(f);
    u += 0x7fffu + ((u >> 16) & 1u);
    return (ushort)(u >> 16);
}
__device__ inline float b2f(ushort u) {
    return __uint_as_float((uint)u << 16);
}

// ---------------- CSR build over (row, colchunk) keys ----------------

__global__ void k_hist(const int* __restrict__ er, const int* __restrict__ ec,
                       int* __restrict__ counts) {
    int i = blockIdx.x * blockDim.x + threadIdx.x;
    int stride = gridDim.x * blockDim.x;
    const int4* r4 = (const int4*)er;
    const int4* c4 = (const int4*)ec;
    for (; i < NE / 4; i += stride) {
        int4 r = r4[i];
        int4 c = c4[i];
        atomicAdd(&counts[(r.x << 4) | (c.x >> 12)], 1);
        atomicAdd(&counts[(r.y << 4) | (c.y >> 12)], 1);
        atomicAdd(&counts[(r.z << 4) | (c.z >> 12)], 1);
        atomicAdd(&counts[(r.w << 4) | (c.w >> 12)], 1);
    }
}

__global__ __launch_bounds__(1024) void k_scanA(const int* __restrict__ counts,
                                                int* __restrict__ rp2,
                                                int* __restrict__ partials) {
    __shared__ int buf[1024];
    const int t = threadIdx.x;
    const int base = blockIdx.x * 4096 + t * 4;
    int v0 = (base + 0 < NC) ? counts[base + 0] : 0;
    int v1 = (base + 1 < NC) ? counts[base + 1] : 0;
    int v2 = (base + 2 < NC) ? counts[base + 2] : 0;
    int v3 = (base + 3 < NC) ? counts[base + 3] : 0;
    int S = v0 + v1 + v2 + v3;
    buf[t] = S;
    __syncthreads();
    for (int off = 1; off < 1024; off <<= 1) {
        int x = (t >= off) ? buf[t - off] : 0;
        __syncthreads();
        buf[t] += x;
        __syncthreads();
    }
    int ex = buf[t] - S;               // exclusive within block
    if (base + 0 < NC) rp2[base + 0] = ex;
    if (base + 1 < NC) rp2[base + 1] = ex + v0;
    if (base + 2 < NC) rp2[base + 2] = ex + v0 + v1;
    if (base + 3 < NC) rp2[base + 3] = ex + v0 + v1 + v2;
    if (t == 1023) partials[blockIdx.x] = buf[1023];
}

__global__ __launch_bounds__(256) void k_scanB(int* __restrict__ partials,
                                               int* __restrict__ rp2) {
    __shared__ int buf[256];
    int t = threadIdx.x;
    int v = (t < SCAN_B) ? partials[t] : 0;
    buf[t] = v;
    __syncthreads();
    for (int off = 1; off < 256; off <<= 1) {
        int x = (t >= off) ? buf[t - off] : 0;
        __syncthreads();
        buf[t] += x;
        __syncthreads();
    }
    if (t < SCAN_B) partials[t] = buf[t] - v;   // exclusive block offsets
    if (t == 255) rp2[NC] = buf[255];
}

__global__ __launch_bounds__(1024) void k_scanC(int* __restrict__ rp2,
                                                int* __restrict__ cur,
                                                const int* __restrict__ partials) {
    const int off = partials[blockIdx.x];
    const int base = blockIdx.x * 4096 + threadIdx.x * 4;
    #pragma unroll
    for (int e = 0; e < 4; ++e) {
        int i = base + e;
        if (i < NC) {
            int x = rp2[i] + off;
            rp2[i] = x;
            cur[i] = x;
        }
    }
}

// ---------------- fat kernel: GEMM1 (MFMA) + XCD-local scatter ----------------

__global__ __launch_bounds__(256) void k_gemm1_scatter(
        const float* __restrict__ X, const float* __restrict__ W,
        const float* __restrict__ B, ushort* __restrict__ H,
        const int* __restrict__ er, const int* __restrict__ ec,
        const float* __restrict__ ev, int* __restrict__ cur,
        uint* __restrict__ e4) {
    const int bid = blockIdx.x;
    if (bid < G1_BLOCKS) {
        __shared__ ushort Xs[128 * 32];
        __shared__ ushort Ws[128 * 32];
        const int bm = (bid >> 1) * 128;
        const int bn = (bid & 1) * 128;
        const int tid = threadIdx.x;
        const int wid = tid >> 6, lane = tid & 63;
        const int wm = wid >> 1, wn = wid & 1;
        const int lr = lane & 15, lg = lane >> 4;

        f32x4 acc[4][4];
        #pragma unroll
        for (int i = 0; i < 4; ++i)
            #pragma unroll
            for (int j = 0; j < 4; ++j)
                acc[i][j] = (f32x4){0.f, 0.f, 0.f, 0.f};

        for (int kt = 0; kt < DI; kt += 32) {
            #pragma unroll
            for (int c = 0; c < 4; ++c) {
                int id = tid + c * 256;
                int row = id >> 3, kc = id & 7;
                int gr = bm + row;
                float4 v = {0.f, 0.f, 0.f, 0.f};
                if (gr < NN) v = *(const float4*)(X + (size_t)gr * DI + kt + kc * 4);
                ushort4 p = make_ushort4(f2b(v.x), f2b(v.y), f2b(v.z), f2b(v.w));
                *(ushort4*)&Xs[row * 32 + kc * 4] = p;
            }
            #pragma unroll
            for (int c = 0; c < 2; ++c) {
                int id = tid + c * 256;
                int n = id & 127, g = id >> 7;
                short8 p;
                #pragma unroll
                for (int e = 0; e < 8; ++e)
                    p[e] = (short)f2b(W[(size_t)(kt + g * 8 + e) * DH + bn + n]);
                *(short8*)&Ws[n * 32 + g * 8] = p;
            }
            __syncthreads();

            short8 a[4], b[4];
            #pragma unroll
            for (int f = 0; f < 4; ++f) {
                a[f] = *(short8*)&Xs[(wm * 64 + f * 16 + lr) * 32 + lg * 8];
                b[f] = *(short8*)&Ws[(wn * 64 + f * 16 + lr) * 32 + lg * 8];
            }
            #pragma unroll
            for (int i = 0; i < 4; ++i)
                #pragma unroll
                for (int j = 0; j < 4; ++j)
                    acc[i][j] = __builtin_amdgcn_mfma_f32_16x16x32_bf16(a[i], b[j], acc[i][j], 0, 0, 0);
            __syncthreads();
        }

        #pragma unroll
        for (int i = 0; i < 4; ++i) {
            int r0 = bm + wm * 64 + i * 16 + lg * 4;
            #pragma unroll
            for (int j = 0; j < 4; ++j) {
                int col = bn + wn * 64 + j * 16 + lr;
                float bias = B[col];
                #pragma unroll
                for (int e = 0; e < 4; ++e) {
                    int r = r0 + e;
                    if (r < NN) H[(size_t)r * DH + col] = f2b(acc[i][j][e] + bias);
                }
            }
        }
    } else {
        // scatter: rows partitioned by XCD (blockIdx % 8); per-XCD write window
        // (~800 KB of e4 + 400 KB of cur) stays L2-resident.
        const int sb = bid - G1_BLOCKS;
        const int g  = bid & 7;
        const int lb = sb >> 3;
        const int lo = g * (NN / 8), hi = lo + (NN / 8);
        const int tid = threadIdx.x;
        const int4* er4 = (const int4*)er;
        const int4* ec4 = (const int4*)ec;
        const float4* ev4 = (const float4*)ev;
        const int NQ = NE / 4;
        for (int q = lb * 256 + tid; q < NQ; q += (SC_BLOCKS / 8) * 256) {
            int4 r4 = er4[q];
            int4 c4 = ec4[q];
            float4 v4 = ev4[q];
            #pragma unroll
            for (int e = 0; e < 4; ++e) {
                int r = (e == 0) ? r4.x : (e == 1) ? r4.y : (e == 2) ? r4.z : r4.w;
                if (r >= lo && r < hi) {
                    int c = (e == 0) ? c4.x : (e == 1) ? c4.y : (e == 2) ? c4.z : c4.w;
                    float v = (e == 0) ? v4.x : (e == 1) ? v4.y : (e == 2) ? v4.z : v4.w;
                    int p = atomicAdd(&cur[(r << 4) | (c >> 12)], 1);
                    e4[p] = (uint)c | ((uint)f2b(v) << 16);
                }
            }
        }
    }
}

// ---------------- SpMM1 + ReLU: persistent, chunk-synchronized ----------------
// 2048 blocks (8/CU, all co-resident). Wave gw owns rows {gw + 8192*k}.
// Outer loop = column chunk: all waves gather from the same 2 MB h1 slice
// at the same time -> slice is L2-resident on every XCD, short reuse distance.

__global__ __launch_bounds__(256) void k_spmm1(const int* __restrict__ rp2,
                                               const uint* __restrict__ e4,
                                               const ushort* __restrict__ H,
                                               ushort* __restrict__ O) {
    const int gw = blockIdx.x * 4 + (threadIdx.x >> 6);   // 0..8191
    const int lane = threadIdx.x & 63;
    const ushort* base = H + lane * 4;

    float acc[ROWS_PW][4];
    int   pos[ROWS_PW];
    #pragma unroll
    for (int k = 0; k < ROWS_PW; ++k) {
        acc[k][0] = acc[k][1] = acc[k][2] = acc[k][3] = 0.f;
        int r = gw + k * P_WAVES;
        pos[k] = (r < NN) ? rp2[r << 4] : 0;
    }

    for (int ch = 0; ch < 13; ++ch) {
        #pragma unroll
        for (int k = 0; k < ROWS_PW; ++k) {
            int r = gw + k * P_WAVES;
            if (r >= NN) continue;
            int i = pos[k];
            int e = rp2[(r << 4) + ch + 1];
            pos[k] = e;
            for (; i + 2 <= e; i += 2) {
                uint u0 = e4[i], u1 = e4[i + 1];
                ushort4 h0 = *(const ushort4*)(base + (size_t)(u0 & 0xffffu) * DH);
                ushort4 h1 = *(const ushort4*)(base + (size_t)(u1 & 0xffffu) * DH);
                float v0 = __uint_as_float(u0 & 0xffff0000u);
                float v1 = __uint_as_float(u1 & 0xffff0000u);
                acc[k][0] += v0 * b2f(h0.x) + v1 * b2f(h1.x);
                acc[k][1] += v0 * b2f(h0.y) + v1 * b2f(h1.y);
                acc[k][2] += v0 * b2f(h0.z) + v1 * b2f(h1.z);
                acc[k][3] += v0 * b2f(h0.w) + v1 * b2f(h1.w);
            }
            if (i < e) {
                uint u0 = e4[i];
                ushort4 h0 = *(const ushort4*)(base + (size_t)(u0 & 0xffffu) * DH);
                float v0 = __uint_as_float(u0 & 0xffff0000u);
                acc[k][0] += v0 * b2f(h0.x);
                acc[k][1] += v0 * b2f(h0.y);
                acc[k][2] += v0 * b2f(h0.z);
                acc[k][3] += v0 * b2f(h0.w);
            }
        }
    }

    #pragma unroll
    for (int k = 0; k < ROWS_PW; ++k) {
        int r = gw + k * P_WAVES;
        if (r >= NN) continue;
        ushort4 o = make_ushort4(f2b(fmaxf(acc[k][0], 0.f)), f2b(fmaxf(acc[k][1], 0.f)),
                                 f2b(fmaxf(acc[k][2], 0.f)), f2b(fmaxf(acc[k][3], 0.f)));
        *(ushort4*)(O + (size_t)r * DH + lane * 4) = o;
    }
}

// ---------------- GEMM2 (MFMA): h2 = h1b @ W2 + b2 ----------------

__global__ __launch_bounds__(256) void k_gemm2(const ushort* __restrict__ HB,
                                               const float* __restrict__ W2,
                                               const float* __restrict__ B2,
                                               ushort* __restrict__ H2) {
    __shared__ ushort Ws[64 * 264];
    const int tid = threadIdx.x;
    for (int idx = tid; idx < DH * DO; idx += 256) {
        int k = idx >> 6, n = idx & 63;
        Ws[n * 264 + k] = f2b(W2[idx]);
    }
    __syncthreads();
    const int wid = tid >> 6, lane = tid & 63;
    const int lr = lane & 15, lg = lane >> 4;
    const int r0 = blockIdx.x * 128 + wid * 32;

    f32x4 acc[2][4];
    #pragma unroll
    for (int i = 0; i < 2; ++i)
        #pragma unroll
        for (int j = 0; j < 4; ++j)
            acc[i][j] = (f32x4){0.f, 0.f, 0.f, 0.f};

    for (int kt = 0; kt < DH; kt += 32) {
        short8 a[2], b[4];
        #pragma unroll
        for (int f = 0; f < 2; ++f) {
            int row = r0 + f * 16 + lr;
            a[f] = (row < NN) ? *(const short8*)(HB + (size_t)row * DH + kt + lg * 8)
                              : (short8){0,0,0,0,0,0,0,0};
        }
        #pragma unroll
        for (int j = 0; j < 4; ++j)
            b[j] = *(const short8*)&Ws[(j * 16 + lr) * 264 + kt + lg * 8];
        #pragma unroll
        for (int i = 0; i < 2; ++i)
            #pragma unroll
            for (int j = 0; j < 4; ++j)
                acc[i][j] = __builtin_amdgcn_mfma_f32_16x16x32_bf16(a[i], b[j], acc[i][j], 0, 0, 0);
    }

    #pragma unroll
    for (int i = 0; i < 2; ++i) {
        #pragma unroll
        for (int j = 0; j < 4; ++j) {
            int col = j * 16 + lr;
            float bias = B2[col];
            #pragma unroll
            for (int e = 0; e < 4; ++e) {
                int row = r0 + i * 16 + lg * 4 + e;
                if (row < NN) H2[(size_t)row * DO + col] = f2b(acc[i][j][e] + bias);
            }
        }
    }
}

// ---------------- SpMM2: out = A @ h2 (h2 3.2 MB, L2-resident everywhere) ----------------
// wave = 8 edge slots x 8 dim-lanes (ushort8 = 16 B each, 8 dims/lane).

__global__ __launch_bounds__(256) void k_spmm_out(const int* __restrict__ rp2,
                                                  const uint* __restrict__ e4,
                                                  const ushort* __restrict__ H2,
                                                  float* __restrict__ OUT) {
    const int r = blockIdx.x * 4 + (threadIdx.x >> 6);
    const int lane = threadIdx.x & 63;
    const int slot = lane >> 3;       // 0..7 edge slot
    const int dq = lane & 7;          // 8 dims each
    const int s = rp2[r << 4], e = rp2[(r + 1) << 4];
    float a[8] = {0.f, 0.f, 0.f, 0.f, 0.f, 0.f, 0.f, 0.f};

    for (int i = s + slot; i < e; i += 8) {
        uint u = e4[i];
        short8 h = *(const short8*)(H2 + (size_t)(u & 0xffffu) * DO + dq * 8);
        float v = __uint_as_float(u & 0xffff0000u);
        #pragma unroll
        for (int d = 0; d < 8; ++d) a[d] += v * b2f((ushort)h[d]);
    }
    #pragma unroll
    for (int d = 0; d < 8; ++d) {
        a[d] += __shfl_xor(a[d], 8);
        a[d] += __shfl_xor(a[d], 16);
        a[d] += __shfl_xor(a[d], 32);
    }
    if (slot == 0) {
        float* o = OUT + (size_t)r * DO + dq * 8;
        *(float4*)o       = make_float4(a[0], a[1], a[2], a[3]);
        *(float4*)(o + 4) = make_float4(a[4], a[5], a[6], a[7]);
    }
}

// ---------------- launch ----------------

extern "C" void kernel_launch(void* const* d_in, const int* in_sizes, int n_in,
                              void* d_out, int out_size, void* d_ws, size_t ws_size,
                              hipStream_t stream) {
    const float* x  = (const float*)d_in[0];
    const int*   er = (const int*)d_in[1];
    const int*   ec = (const int*)d_in[2];
    const float* ev = (const float*)d_in[3];
    const float* W1 = (const float*)d_in[4];
    const float* b1 = (const float*)d_in[5];
    const float* W2 = (const float*)d_in[6];
    const float* b2 = (const float*)d_in[7];
    float* out = (float*)d_out;

    char* ws = (char*)d_ws;
    ushort* h1  = (ushort*)ws; ws += (size_t)NN * DH * 2;                    // 25.6 MB
    ushort* h1b = (ushort*)ws; ws += (size_t)NN * DH * 2;                    // 25.6 MB
    ushort* h2  = (ushort*)ws; ws += (size_t)NN * DO * 2;                    //  6.4 MB
    uint*  e4   = (uint*)ws;   ws += (size_t)NE * 4;                         //  6.4 MB
    int* counts = (int*)ws;    ws += ((size_t)NC * 4 + 255) & ~(size_t)255;  //  3.2 MB
    int* rp2    = (int*)ws;    ws += ((size_t)(NC + 1) * 4 + 255) & ~(size_t)255;
    int* cur    = (int*)ws;    ws += ((size_t)NC * 4 + 255) & ~(size_t)255;
    int* partials = (int*)ws;  ws += 1024;

    hipMemsetAsync(counts, 0, (size_t)NC * 4, stream);
    k_hist<<<1024, 256, 0, stream>>>(er, ec, counts);
    k_scanA<<<SCAN_B, 1024, 0, stream>>>(counts, rp2, partials);
    k_scanB<<<1, 256, 0, stream>>>(partials, rp2);
    k_scanC<<<SCAN_B, 1024, 0, stream>>>(rp2, cur, partials);
    k_gemm1_scatter<<<G1_BLOCKS + SC_BLOCKS, 256, 0, stream>>>(
        x, W1, b1, h1, er, ec, ev, cur, e4);
    k_spmm1<<<P_BLOCKS, 256, 0, stream>>>(rp2, e4, h1, h1b);
    k_gemm2<<<(NN + 127) / 128, 256, 0, stream>>>(h1b, W2, b2, h2);
    k_spmm_out<<<NN / 4, 256, 0, stream>>>(rp2, e4, h2, out);
}

// Round 6
// 394.731 us; speedup vs baseline: 1.4596x; 1.1406x over previous
//
#include <hip/hip_runtime.h>
#include <hip/hip_bf16.h>

constexpr int NN = 50000;
constexpr int NE = 1600000;
constexpr int DI = 512;
constexpr int DH = 256;
constexpr int DO = 64;

constexpr int NCH = 16;                  // column chunks: chunk = col >> 12 (13 used)
constexpr int NC  = NN * NCH;            // 800000 keys
constexpr int SCAN_B = (NC + 4095) / 4096;   // 196 blocks
constexpr int G1_BLOCKS = ((NN + 127) / 128) * (DH / 128);  // 782
constexpr int SC_BLOCKS = 2048;

typedef __attribute__((ext_vector_type(8))) short short8;
typedef __attribute__((ext_vector_type(4))) float f32x4;

__device__ inline ushort f2b(float f) {          // fp32 -> bf16 bits, RNE
    uint u = __float_as_uint(f);
    u += 0x7fffu + ((u >> 16) & 1u);
    return (ushort)(u >> 16);
}
__device__ inline float b2f(ushort u) {
    return __uint_as_float((uint)u << 16);
}

// ---------------- CSR build over (row, colchunk) keys ----------------

__global__ void k_hist(const int* __restrict__ er, const int* __restrict__ ec,
                       int* __restrict__ counts) {
    int i = blockIdx.x * blockDim.x + threadIdx.x;
    int stride = gridDim.x * blockDim.x;
    const int4* r4 = (const int4*)er;
    const int4* c4 = (const int4*)ec;
    for (; i < NE / 4; i += stride) {
        int4 r = r4[i];
        int4 c = c4[i];
        atomicAdd(&counts[(r.x << 4) | (c.x >> 12)], 1);
        atomicAdd(&counts[(r.y << 4) | (c.y >> 12)], 1);
        atomicAdd(&counts[(r.z << 4) | (c.z >> 12)], 1);
        atomicAdd(&counts[(r.w << 4) | (c.w >> 12)], 1);
    }
}

__global__ __launch_bounds__(1024) void k_scanA(const int* __restrict__ counts,
                                                int* __restrict__ rp2,
                                                int* __restrict__ partials) {
    __shared__ int buf[1024];
    const int t = threadIdx.x;
    const int base = blockIdx.x * 4096 + t * 4;
    int v0 = (base + 0 < NC) ? counts[base + 0] : 0;
    int v1 = (base + 1 < NC) ? counts[base + 1] : 0;
    int v2 = (base + 2 < NC) ? counts[base + 2] : 0;
    int v3 = (base + 3 < NC) ? counts[base + 3] : 0;
    int S = v0 + v1 + v2 + v3;
    buf[t] = S;
    __syncthreads();
    for (int off = 1; off < 1024; off <<= 1) {
        int x = (t >= off) ? buf[t - off] : 0;
        __syncthreads();
        buf[t] += x;
        __syncthreads();
    }
    int ex = buf[t] - S;
    if (base + 0 < NC) rp2[base + 0] = ex;
    if (base + 1 < NC) rp2[base + 1] = ex + v0;
    if (base + 2 < NC) rp2[base + 2] = ex + v0 + v1;
    if (base + 3 < NC) rp2[base + 3] = ex + v0 + v1 + v2;
    if (t == 1023) partials[blockIdx.x] = buf[1023];
}

__global__ __launch_bounds__(256) void k_scanB(int* __restrict__ partials,
                                               int* __restrict__ rp2) {
    __shared__ int buf[256];
    int t = threadIdx.x;
    int v = (t < SCAN_B) ? partials[t] : 0;
    buf[t] = v;
    __syncthreads();
    for (int off = 1; off < 256; off <<= 1) {
        int x = (t >= off) ? buf[t - off] : 0;
        __syncthreads();
        buf[t] += x;
        __syncthreads();
    }
    if (t < SCAN_B) partials[t] = buf[t] - v;
    if (t == 255) rp2[NC] = buf[255];
}

__global__ __launch_bounds__(1024) void k_scanC(int* __restrict__ rp2,
                                                int* __restrict__ cur,
                                                const int* __restrict__ partials,
                                                const float* __restrict__ W2,
                                                ushort* __restrict__ w2b) {
    const int off = partials[blockIdx.x];
    const int base = blockIdx.x * 4096 + threadIdx.x * 4;
    #pragma unroll
    for (int e = 0; e < 4; ++e) {
        int i = base + e;
        if (i < NC) {
            int x = rp2[i] + off;
            rp2[i] = x;
            cur[i] = x;
        }
    }
    // block 0 also converts W2 (256x64 fp32) to bf16 once
    if (blockIdx.x == 0) {
        for (int i = threadIdx.x; i < DH * DO; i += 1024)
            w2b[i] = f2b(W2[i]);
    }
}

// ---------------- fat kernel: GEMM1 (MFMA) + XCD-local scatter ----------------

__global__ __launch_bounds__(256) void k_gemm1_scatter(
        const float* __restrict__ X, const float* __restrict__ W,
        const float* __restrict__ B, ushort* __restrict__ H,
        const int* __restrict__ er, const int* __restrict__ ec,
        const float* __restrict__ ev, int* __restrict__ cur,
        uint* __restrict__ e4) {
    const int bid = blockIdx.x;
    if (bid < G1_BLOCKS) {
        __shared__ ushort Xs[128 * 32];
        __shared__ ushort Ws[128 * 32];
        const int bm = (bid >> 1) * 128;
        const int bn = (bid & 1) * 128;
        const int tid = threadIdx.x;
        const int wid = tid >> 6, lane = tid & 63;
        const int wm = wid >> 1, wn = wid & 1;
        const int lr = lane & 15, lg = lane >> 4;

        f32x4 acc[4][4];
        #pragma unroll
        for (int i = 0; i < 4; ++i)
            #pragma unroll
            for (int j = 0; j < 4; ++j)
                acc[i][j] = (f32x4){0.f, 0.f, 0.f, 0.f};

        for (int kt = 0; kt < DI; kt += 32) {
            #pragma unroll
            for (int c = 0; c < 4; ++c) {
                int id = tid + c * 256;
                int row = id >> 3, kc = id & 7;
                int gr = bm + row;
                float4 v = {0.f, 0.f, 0.f, 0.f};
                if (gr < NN) v = *(const float4*)(X + (size_t)gr * DI + kt + kc * 4);
                ushort4 p = make_ushort4(f2b(v.x), f2b(v.y), f2b(v.z), f2b(v.w));
                *(ushort4*)&Xs[row * 32 + kc * 4] = p;
            }
            #pragma unroll
            for (int c = 0; c < 2; ++c) {
                int id = tid + c * 256;
                int n = id & 127, g = id >> 7;
                short8 p;
                #pragma unroll
                for (int e = 0; e < 8; ++e)
                    p[e] = (short)f2b(W[(size_t)(kt + g * 8 + e) * DH + bn + n]);
                *(short8*)&Ws[n * 32 + g * 8] = p;
            }
            __syncthreads();

            short8 a[4], b[4];
            #pragma unroll
            for (int f = 0; f < 4; ++f) {
                a[f] = *(short8*)&Xs[(wm * 64 + f * 16 + lr) * 32 + lg * 8];
                b[f] = *(short8*)&Ws[(wn * 64 + f * 16 + lr) * 32 + lg * 8];
            }
            #pragma unroll
            for (int i = 0; i < 4; ++i)
                #pragma unroll
                for (int j = 0; j < 4; ++j)
                    acc[i][j] = __builtin_amdgcn_mfma_f32_16x16x32_bf16(a[i], b[j], acc[i][j], 0, 0, 0);
            __syncthreads();
        }

        #pragma unroll
        for (int i = 0; i < 4; ++i) {
            int r0 = bm + wm * 64 + i * 16 + lg * 4;
            #pragma unroll
            for (int j = 0; j < 4; ++j) {
                int col = bn + wn * 64 + j * 16 + lr;
                float bias = B[col];
                #pragma unroll
                for (int e = 0; e < 4; ++e) {
                    int r = r0 + e;
                    if (r < NN) H[(size_t)r * DH + col] = f2b(acc[i][j][e] + bias);
                }
            }
        }
    } else {
        // scatter: rows partitioned by XCD (blockIdx % 8); per-XCD write window
        // (~800 KB of e4 + 400 KB of cur) stays L2-resident.
        const int sb = bid - G1_BLOCKS;
        const int g  = bid & 7;
        const int lb = sb >> 3;
        const int lo = g * (NN / 8), hi = lo + (NN / 8);
        const int tid = threadIdx.x;
        const int4* er4 = (const int4*)er;
        const int4* ec4 = (const int4*)ec;
        const float4* ev4 = (const float4*)ev;
        const int NQ = NE / 4;
        for (int q = lb * 256 + tid; q < NQ; q += (SC_BLOCKS / 8) * 256) {
            int4 r4 = er4[q];
            int4 c4 = ec4[q];
            float4 v4 = ev4[q];
            #pragma unroll
            for (int e = 0; e < 4; ++e) {
                int r = (e == 0) ? r4.x : (e == 1) ? r4.y : (e == 2) ? r4.z : r4.w;
                if (r >= lo && r < hi) {
                    int c = (e == 0) ? c4.x : (e == 1) ? c4.y : (e == 2) ? c4.z : c4.w;
                    float v = (e == 0) ? v4.x : (e == 1) ? v4.y : (e == 2) ? v4.z : v4.w;
                    int p = atomicAdd(&cur[(r << 4) | (c >> 12)], 1);
                    e4[p] = (uint)c | ((uint)f2b(v) << 16);
                }
            }
        }
    }
}

// ---------------- fused SpMM1 + ReLU + GEMM2 ----------------
// wave per row, flat scan of the CHUNK-SORTED edge stream (temporal locality
// comes from the sort: co-resident waves sweep columns in the same order).
// 8 gathers in flight per wave. Phase 2: x W2 + b2 -> h2 (bf16).

__global__ __launch_bounds__(256) void k_srg(const int* __restrict__ rp2,
                                             const uint* __restrict__ e4,
                                             const ushort* __restrict__ H,
                                             const ushort* __restrict__ w2b,
                                             const float* __restrict__ B2,
                                             ushort* __restrict__ H2) {
    __shared__ float hs[4][DH];
    const int tid = threadIdx.x;
    const int w = tid >> 6, lane = tid & 63;
    const int r = blockIdx.x * 4 + w;
    const int s = rp2[r << 4], e = rp2[(r + 1) << 4];
    const ushort* base = H + lane * 4;

    float a0 = 0.f, a1 = 0.f, a2 = 0.f, a3 = 0.f;
    int i = s;
    for (; i + 8 <= e; i += 8) {
        uint u[8];
        #pragma unroll
        for (int k = 0; k < 8; ++k) u[k] = e4[i + k];
        ushort4 h[8];
        #pragma unroll
        for (int k = 0; k < 8; ++k)
            h[k] = *(const ushort4*)(base + (size_t)(u[k] & 0xffffu) * DH);
        #pragma unroll
        for (int k = 0; k < 8; ++k) {
            float v = __uint_as_float(u[k] & 0xffff0000u);
            a0 += v * b2f(h[k].x);
            a1 += v * b2f(h[k].y);
            a2 += v * b2f(h[k].z);
            a3 += v * b2f(h[k].w);
        }
    }
    for (; i < e; ++i) {
        uint u = e4[i];
        ushort4 h = *(const ushort4*)(base + (size_t)(u & 0xffffu) * DH);
        float v = __uint_as_float(u & 0xffff0000u);
        a0 += v * b2f(h.x); a1 += v * b2f(h.y); a2 += v * b2f(h.z); a3 += v * b2f(h.w);
    }
    *(float4*)&hs[w][lane * 4] = make_float4(fmaxf(a0, 0.f), fmaxf(a1, 0.f),
                                             fmaxf(a2, 0.f), fmaxf(a3, 0.f));
    __syncthreads();

    const int rr = tid >> 6;
    const int j  = tid & 63;
    float acc = B2[j];
    #pragma unroll 8
    for (int k = 0; k < DH; ++k) acc += hs[rr][k] * b2f(w2b[k * DO + j]);
    H2[(size_t)(blockIdx.x * 4 + rr) * DO + j] = f2b(acc);
}

// ---------------- SpMM2: out = A @ h2 ----------------
// wave = 8 edge slots x 8 dim-lanes (ushort8 = 16 B each).

__global__ __launch_bounds__(256) void k_spmm_out(const int* __restrict__ rp2,
                                                  const uint* __restrict__ e4,
                                                  const ushort* __restrict__ H2,
                                                  float* __restrict__ OUT) {
    const int r = blockIdx.x * 4 + (threadIdx.x >> 6);
    const int lane = threadIdx.x & 63;
    const int slot = lane >> 3;
    const int dq = lane & 7;
    const int s = rp2[r << 4], e = rp2[(r + 1) << 4];
    float a[8] = {0.f, 0.f, 0.f, 0.f, 0.f, 0.f, 0.f, 0.f};

    for (int i = s + slot; i < e; i += 8) {
        uint u = e4[i];
        short8 h = *(const short8*)(H2 + (size_t)(u & 0xffffu) * DO + dq * 8);
        float v = __uint_as_float(u & 0xffff0000u);
        #pragma unroll
        for (int d = 0; d < 8; ++d) a[d] += v * b2f((ushort)h[d]);
    }
    #pragma unroll
    for (int d = 0; d < 8; ++d) {
        a[d] += __shfl_xor(a[d], 8);
        a[d] += __shfl_xor(a[d], 16);
        a[d] += __shfl_xor(a[d], 32);
    }
    if (slot == 0) {
        float* o = OUT + (size_t)r * DO + dq * 8;
        *(float4*)o       = make_float4(a[0], a[1], a[2], a[3]);
        *(float4*)(o + 4) = make_float4(a[4], a[5], a[6], a[7]);
    }
}

// ---------------- launch ----------------

extern "C" void kernel_launch(void* const* d_in, const int* in_sizes, int n_in,
                              void* d_out, int out_size, void* d_ws, size_t ws_size,
                              hipStream_t stream) {
    const float* x  = (const float*)d_in[0];
    const int*   er = (const int*)d_in[1];
    const int*   ec = (const int*)d_in[2];
    const float* ev = (const float*)d_in[3];
    const float* W1 = (const float*)d_in[4];
    const float* b1 = (const float*)d_in[5];
    const float* W2 = (const float*)d_in[6];
    const float* b2 = (const float*)d_in[7];
    float* out = (float*)d_out;

    char* ws = (char*)d_ws;
    ushort* h1  = (ushort*)ws; ws += (size_t)NN * DH * 2;                    // 25.6 MB
    ushort* h2  = (ushort*)ws; ws += (size_t)NN * DO * 2;                    //  6.4 MB
    uint*  e4   = (uint*)ws;   ws += (size_t)NE * 4;                         //  6.4 MB
    int* counts = (int*)ws;    ws += ((size_t)NC * 4 + 255) & ~(size_t)255;  //  3.2 MB
    int* rp2    = (int*)ws;    ws += ((size_t)(NC + 1) * 4 + 255) & ~(size_t)255;
    int* cur    = (int*)ws;    ws += ((size_t)NC * 4 + 255) & ~(size_t)255;
    int* partials = (int*)ws;  ws += 1024;
    ushort* w2b = (ushort*)ws; ws += ((size_t)DH * DO * 2 + 255) & ~(size_t)255;

    hipMemsetAsync(counts, 0, (size_t)NC * 4, stream);
    k_hist<<<1024, 256, 0, stream>>>(er, ec, counts);
    k_scanA<<<SCAN_B, 1024, 0, stream>>>(counts, rp2, partials);
    k_scanB<<<1, 256, 0, stream>>>(partials, rp2);
    k_scanC<<<SCAN_B, 1024, 0, stream>>>(rp2, cur, partials, W2, w2b);
    k_gemm1_scatter<<<G1_BLOCKS + SC_BLOCKS, 256, 0, stream>>>(
        x, W1, b1, h1, er, ec, ev, cur, e4);
    k_srg<<<NN / 4, 256, 0, stream>>>(rp2, e4, h1, w2b, b2, h2);
    k_spmm_out<<<NN / 4, 256, 0, stream>>>(rp2, e4, h2, out);
}